// Round 2
// baseline (1140.256 us; speedup 1.0000x reference)
//
#include <hip/hip_runtime.h>
#include <math.h>

#define HID 256
#define TS 8
#define SC (TS*4)        // 32 columns: 8 samples x {h/z, dh_0, dh_1, dh_2}
#define THREADS 256
#define EPS_REG 1e-6

// ---------------------------------------------------------------------------
// Transpose W1 (256x256) into d_ws so phase-1 reduction loads are coalesced.
// W1T[j][i] = W1[i][j]
// ---------------------------------------------------------------------------
__global__ void transpose_w1(const float* __restrict__ W1, float* __restrict__ W1T) {
    __shared__ float tile[32][33];
    const int bx = blockIdx.x & 7;        // j-tile
    const int by = blockIdx.x >> 3;       // i-tile
    const int tx = threadIdx.x & 31;
    const int ty = threadIdx.x >> 5;
#pragma unroll
    for (int q = 0; q < 4; ++q)
        tile[ty + q*8][tx] = W1[(by*32 + ty + q*8)*HID + bx*32 + tx];
    __syncthreads();
#pragma unroll
    for (int q = 0; q < 4; ++q)
        W1T[(bx*32 + ty + q*8)*HID + by*32 + tx] = tile[tx][ty + q*8];
}

// ---------------------------------------------------------------------------
// Fused LNN kernel: grad + 3 HVPs + assemble + 3x3 fp64 solve, 8 samples/block
// LDS layout TRANSPOSED vs round-1: [col][HID] so fixed-col lane-varying-row
// accesses are bank-spread; hot-loop reads become broadcast float4 along j.
// ---------------------------------------------------------------------------
__global__ __launch_bounds__(THREADS, 2)
void lnn_fused(const float* __restrict__ x,
               const float* __restrict__ W0, const float* __restrict__ b0,
               const float* __restrict__ W1, const float* __restrict__ b1,
               const float* __restrict__ W2,
               const float* __restrict__ W1T, const int useT,
               float* __restrict__ out)
{
    __shared__ float M0T[SC][HID];  // [s*4+q][j]: q=0 -> h0 ; q=1..3 -> sg*W0[j][4+k]
    __shared__ float UT [SC][HID];  // phase1 out (u1,du1) ; later (u0,du0)

    const int tid   = threadIdx.x;
    const int samp0 = blockIdx.x * TS;

    // ---- Phase 0: first layer forward + tangents --------------------------
    {
        const int j = tid;
        float w0r[7];
#pragma unroll
        for (int d = 0; d < 7; ++d) w0r[d] = W0[j*7 + d];
        const float bj = b0[j];
#pragma unroll
        for (int s = 0; s < TS; ++s) {
            const float* xs = x + (size_t)(samp0 + s)*7;
            float z = bj;
#pragma unroll
            for (int d = 0; d < 7; ++d) z = fmaf(w0r[d], xs[d], z);
            const float h  = tanhf(z);
            const float sg = 1.0f - h*h;
            M0T[s*4+0][j] = h;              // bank = j%32 -> spread, conflict-free
            M0T[s*4+1][j] = sg * w0r[4];
            M0T[s*4+2][j] = sg * w0r[5];
            M0T[s*4+3][j] = sg * w0r[6];
        }
    }
    __syncthreads();

    const int it = tid & 63;    // row tile: i = it*4+r
    const int ct = tid >> 6;    // column group: sc = ct*8 + c (samples 2ct, 2ct+1)

    // ---- Phase 1: Z[i][sc] = sum_j W1[i][j] * M0[j][sc] -------------------
    float acc[4][8];
#pragma unroll
    for (int r = 0; r < 4; ++r)
#pragma unroll
        for (int c = 0; c < 8; ++c) acc[r][c] = 0.0f;

    for (int jb = 0; jb < HID; jb += 4) {
        float4 w[4];
        if (useT) {
#pragma unroll
            for (int jj = 0; jj < 4; ++jj)
                w[jj] = *(const float4*)(W1T + (size_t)(jb + jj)*HID + it*4);
        } else {
#pragma unroll
            for (int jj = 0; jj < 4; ++jj)
#pragma unroll
                for (int r = 0; r < 4; ++r)
                    ((float*)&w[jj])[r] = W1[(size_t)(it*4 + r)*HID + jb + jj];
        }
        float4 m[8];
#pragma unroll
        for (int c = 0; c < 8; ++c)
            m[c] = *(const float4*)(&M0T[ct*8 + c][jb]);   // wave-uniform broadcast
#pragma unroll
        for (int jj = 0; jj < 4; ++jj)
#pragma unroll
            for (int r = 0; r < 4; ++r)
#pragma unroll
                for (int c = 0; c < 8; ++c)
                    acc[r][c] = fmaf(((const float*)&w[jj])[r],
                                     ((const float*)&m[c])[jj], acc[r][c]);
    }

    // ---- Epilogue 1: layer-2 nonlinearity + reverse seed ------------------
    {
        float b1v[4], w2v[4];
#pragma unroll
        for (int r = 0; r < 4; ++r) { b1v[r] = b1[it*4 + r]; w2v[r] = W2[it*4 + r]; }
#pragma unroll
        for (int cs = 0; cs < 2; ++cs) {
            float u1v[4], m2v[4];
#pragma unroll
            for (int r = 0; r < 4; ++r) {
                const float z1 = acc[r][cs*4+0] + b1v[r];
                const float h1 = tanhf(z1);
                const float s1 = 1.0f - h1*h1;
                u1v[r] = w2v[r] * s1;                 // dL/dz1
                m2v[r] = -2.0f * w2v[r] * h1 * s1;    // du1 = m2 * dz1
            }
            float4 v0 = {u1v[0], u1v[1], u1v[2], u1v[3]};
            *(float4*)(&UT[ct*8 + cs*4 + 0][it*4]) = v0;   // banks spread by it
#pragma unroll
            for (int q = 1; q < 4; ++q) {
                float4 vq = {m2v[0]*acc[0][cs*4+q], m2v[1]*acc[1][cs*4+q],
                             m2v[2]*acc[2][cs*4+q], m2v[3]*acc[3][cs*4+q]};
                *(float4*)(&UT[ct*8 + cs*4 + q][it*4]) = vq;
            }
        }
    }
    __syncthreads();

    // ---- Phase 2: P[j][sc] = sum_i W1[i][j] * U[i][sc] --------------------
    float acc2[4][8];
#pragma unroll
    for (int r = 0; r < 4; ++r)
#pragma unroll
        for (int c = 0; c < 8; ++c) acc2[r][c] = 0.0f;

    for (int ib = 0; ib < HID; ib += 4) {
        float4 w[4];
#pragma unroll
        for (int ii = 0; ii < 4; ++ii)
            w[ii] = *(const float4*)(W1 + (size_t)(ib + ii)*HID + it*4);  // coalesced rows
        float4 u[8];
#pragma unroll
        for (int c = 0; c < 8; ++c)
            u[c] = *(const float4*)(&UT[ct*8 + c][ib]);    // broadcast
#pragma unroll
        for (int ii = 0; ii < 4; ++ii)
#pragma unroll
            for (int r = 0; r < 4; ++r)
#pragma unroll
                for (int c = 0; c < 8; ++c)
                    acc2[r][c] = fmaf(((const float*)&w[ii])[r],
                                      ((const float*)&u[c])[ii], acc2[r][c]);
    }
    __syncthreads();    // all u1/du1 reads complete before UT overwrite

    // ---- Epilogue 2: back through layer-0 nonlinearity --> u0, du0 --------
    {
#pragma unroll
        for (int cs = 0; cs < 2; ++cs) {
            const int s = ct*2 + cs;       // sample within tile
            float4 hv[4];
#pragma unroll
            for (int q = 0; q < 4; ++q)
                hv[q] = *(const float4*)(&M0T[s*4 + q][it*4]);   // banks spread by it
            float u0v[4], d0v[4], d1v[4], d2v[4];
#pragma unroll
            for (int r = 0; r < 4; ++r) {
                const float h0v = ((const float*)&hv[0])[r];
                const float sg  = 1.0f - h0v*h0v;
                const float p   = acc2[r][cs*4+0];
                const float t2  = -2.0f * p * h0v;
                u0v[r] = p * sg;
                d0v[r] = fmaf(acc2[r][cs*4+1], sg, t2 * ((const float*)&hv[1])[r]);
                d1v[r] = fmaf(acc2[r][cs*4+2], sg, t2 * ((const float*)&hv[2])[r]);
                d2v[r] = fmaf(acc2[r][cs*4+3], sg, t2 * ((const float*)&hv[3])[r]);
            }
            float4 a0 = {u0v[0], u0v[1], u0v[2], u0v[3]};
            float4 a1 = {d0v[0], d0v[1], d0v[2], d0v[3]};
            float4 a2 = {d1v[0], d1v[1], d1v[2], d1v[3]};
            float4 a3 = {d2v[0], d2v[1], d2v[2], d2v[3]};
            *(float4*)(&UT[s*4 + 0][it*4]) = a0;
            *(float4*)(&UT[s*4 + 1][it*4]) = a1;
            *(float4*)(&UT[s*4 + 2][it*4]) = a2;
            *(float4*)(&UT[s*4 + 3][it*4]) = a3;
        }
    }
    __syncthreads();

    // ---- Phase 3: project through W0^T, reduce, assemble, solve -----------
    const int s = tid >> 5;     // sample within tile (0..7)
    const int t = tid & 31;     // 32 threads per sample
    float part[25];             // [0..3]=grad d<4 ; [4+k*7+d]=hvp_k[d]
#pragma unroll
    for (int q = 0; q < 25; ++q) part[q] = 0.0f;

#pragma unroll
    for (int m = 0; m < 8; ++m) {
        const int j = t + 32*m;
        const float u0 = UT[s*4+0][j];   // bank = j%32 = t -> conflict-free
        const float e0 = UT[s*4+1][j];
        const float e1 = UT[s*4+2][j];
        const float e2 = UT[s*4+3][j];
        float w0d[7];
#pragma unroll
        for (int d = 0; d < 7; ++d) w0d[d] = W0[j*7 + d];
#pragma unroll
        for (int d = 0; d < 4; ++d) part[d] = fmaf(u0, w0d[d], part[d]);
#pragma unroll
        for (int d = 0; d < 7; ++d) {
            part[4  + d] = fmaf(e0, w0d[d], part[4  + d]);
            part[11 + d] = fmaf(e1, w0d[d], part[11 + d]);
            part[18 + d] = fmaf(e2, w0d[d], part[18 + d]);
        }
    }
    // reduce across the 32 threads of this sample (stays within 32-lane half)
#pragma unroll
    for (int off = 16; off >= 1; off >>= 1)
#pragma unroll
        for (int q = 0; q < 25; ++q)
            part[q] += __shfl_xor(part[q], off, 64);

    if (t == 0) {
        const float* xs = x + (size_t)(samp0 + s)*7;
        const double x1 = xs[2], x2 = xs[3];
        const double dq0 = xs[4], dq1 = xs[5], dth = xs[6];

        double A[3][4];
#pragma unroll
        for (int i = 0; i < 3; ++i) {
            const double J0 = part[4 + i*7 + 0];
            const double J1 = part[4 + i*7 + 1];
            const double J2 = -x2*(double)part[4 + i*7 + 2] + x1*(double)part[4 + i*7 + 3];
            const double dL = (i == 0) ? (double)part[0]
                            : (i == 1) ? (double)part[1]
                            : (-x2*(double)part[2] + x1*(double)part[3]);
            A[i][0] = (double)part[4 + i*7 + 4] + (i == 0 ? EPS_REG : 0.0);
            A[i][1] = (double)part[4 + i*7 + 5] + (i == 1 ? EPS_REG : 0.0);
            A[i][2] = (double)part[4 + i*7 + 6] + (i == 2 ? EPS_REG : 0.0);
            A[i][3] = dL - (J0*dq0 + J1*dq1 + J2*dth);
        }
        // 3x3 Gaussian elimination with partial pivoting (fp64)
        for (int c = 0; c < 2; ++c) {
            int piv = c;
            double mx = fabs(A[c][c]);
            for (int rr = c + 1; rr < 3; ++rr) {
                const double v = fabs(A[rr][c]);
                if (v > mx) { mx = v; piv = rr; }
            }
            if (piv != c) {
                for (int cc = 0; cc < 4; ++cc) {
                    const double tmp = A[c][cc]; A[c][cc] = A[piv][cc]; A[piv][cc] = tmp;
                }
            }
            const double inv = 1.0 / A[c][c];
            for (int rr = c + 1; rr < 3; ++rr) {
                const double f = A[rr][c] * inv;
                for (int cc = c + 1; cc < 4; ++cc) A[rr][cc] -= f * A[c][cc];
            }
        }
        const double sol2 = A[2][3] / A[2][2];
        const double sol1 = (A[1][3] - A[1][2]*sol2) / A[1][1];
        const double sol0 = (A[0][3] - A[0][1]*sol1 - A[0][2]*sol2) / A[0][0];

        float* o = out + (size_t)(samp0 + s)*7;
        o[0] = (float)dq0;
        o[1] = (float)dq1;
        o[2] = (float)(-x2*dth);
        o[3] = (float)( x1*dth);
        o[4] = (float)sol0;
        o[5] = (float)sol1;
        o[6] = (float)sol2;
    }
}

extern "C" void kernel_launch(void* const* d_in, const int* in_sizes, int n_in,
                              void* d_out, int out_size, void* d_ws, size_t ws_size,
                              hipStream_t stream) {
    const float* x  = (const float*)d_in[0];
    const float* W0 = (const float*)d_in[1];
    const float* b0 = (const float*)d_in[2];
    const float* W1 = (const float*)d_in[3];
    const float* b1 = (const float*)d_in[4];
    const float* W2 = (const float*)d_in[5];
    // d_in[6] = b2 : unused (gradient of constant)
    float* out = (float*)d_out;

    const int B = in_sizes[0] / 7;
    const int useT = (ws_size >= (size_t)HID * HID * sizeof(float)) ? 1 : 0;
    float* W1T = (float*)d_ws;

    if (useT) transpose_w1<<<64, 256, 0, stream>>>(W1, W1T);
    lnn_fused<<<B / TS, THREADS, 0, stream>>>(x, W0, b0, W1, b1, W2, W1T, useT, out);
}

// Round 3
// 541.677 us; speedup vs baseline: 2.1050x; 2.1050x over previous
//
#include <hip/hip_runtime.h>
#include <math.h>

#define HID 256
#define TS 8
#define SC (TS*4)        // 32 columns: 8 samples x {h, dh0_0, dh0_1, dh0_2}
#define SCP 36           // padded row stride (floats): 144B, 16B-aligned, bank=(4j+c)%32
#define THREADS 256
#define EPS_REG 1e-6

// ---------------------------------------------------------------------------
// Transpose W1 (256x256) into d_ws so phase-1 reduction loads are coalesced.
// W1T[j][i] = W1[i][j]
// ---------------------------------------------------------------------------
__global__ void transpose_w1(const float* __restrict__ W1, float* __restrict__ W1T) {
    __shared__ float tile[32][33];
    const int bx = blockIdx.x & 7;        // j-tile
    const int by = blockIdx.x >> 3;       // i-tile
    const int tx = threadIdx.x & 31;
    const int ty = threadIdx.x >> 5;
#pragma unroll
    for (int q = 0; q < 4; ++q)
        tile[ty + q*8][tx] = W1[(by*32 + ty + q*8)*HID + bx*32 + tx];
    __syncthreads();
#pragma unroll
    for (int q = 0; q < 4; ++q)
        W1T[(bx*32 + ty + q*8)*HID + by*32 + tx] = tile[tx][ty + q*8];
}

// ---------------------------------------------------------------------------
// Fused LNN kernel: grad + 3 HVPs + assemble + 3x3 fp64 solve, 8 samples/block
// Round-1 structure (proven hot loops: broadcast LDS reads, unroll 4, branch
// hoisted) + stride-36 LDS rows to kill the phase-0/epilogue/phase-3 bank
// conflicts (bank=(4j+c)%32 spreads lane-varying-j accesses over all banks).
// ---------------------------------------------------------------------------
__global__ __launch_bounds__(THREADS, 2)
void lnn_fused(const float* __restrict__ x,
               const float* __restrict__ W0, const float* __restrict__ b0,
               const float* __restrict__ W1, const float* __restrict__ b1,
               const float* __restrict__ W2,
               const float* __restrict__ W1T, const int useT,
               float* __restrict__ out)
{
    __shared__ float M0[HID * SCP];   // [j][c]: c=s*4+q ; q=0 -> h0 ; q=1..3 -> sg*W0[j][4+k]
    __shared__ float U [HID * SCP];   // phase1 out (u1,du1) ; later (u0,du0)

    const int tid   = threadIdx.x;
    const int samp0 = blockIdx.x * TS;

    // ---- Phase 0: first layer forward + tangents --------------------------
    {
        const int j = tid;
        float w0r[7];
#pragma unroll
        for (int d = 0; d < 7; ++d) w0r[d] = W0[j*7 + d];
        const float bj = b0[j];
#pragma unroll
        for (int s = 0; s < TS; ++s) {
            const float* xs = x + (size_t)(samp0 + s)*7;
            float z = bj;
#pragma unroll
            for (int d = 0; d < 7; ++d) z = fmaf(w0r[d], xs[d], z);
            const float h  = tanhf(z);
            const float sg = 1.0f - h*h;
            float4 v = {h, sg * w0r[4], sg * w0r[5], sg * w0r[6]};
            *(float4*)(&M0[j*SCP + s*4]) = v;   // banks (4j+4s)%32: full spread
        }
    }
    __syncthreads();

    const int it = tid & 63;    // row tile: i = it*4+r
    const int ct = tid >> 6;    // column group: sc = ct*8 + c

    // ---- Phase 1: Z[i][sc] = sum_j W1[i][j] * M0[j][sc] -------------------
    float acc[4][8];
#pragma unroll
    for (int r = 0; r < 4; ++r)
#pragma unroll
        for (int c = 0; c < 8; ++c) acc[r][c] = 0.0f;

    if (useT) {
#pragma unroll 4
        for (int j = 0; j < HID; ++j) {
            const float4 w4 = *(const float4*)(W1T + (size_t)j*HID + it*4);
            const float4 ma = *(const float4*)(&M0[j*SCP + ct*8]);      // broadcast
            const float4 mb = *(const float4*)(&M0[j*SCP + ct*8 + 4]);  // broadcast
            const float w[4] = {w4.x, w4.y, w4.z, w4.w};
            const float m[8] = {ma.x, ma.y, ma.z, ma.w, mb.x, mb.y, mb.z, mb.w};
#pragma unroll
            for (int r = 0; r < 4; ++r)
#pragma unroll
                for (int c = 0; c < 8; ++c)
                    acc[r][c] = fmaf(w[r], m[c], acc[r][c]);
        }
    } else {
        // fallback: ws too small for W1T -- row-gather (slow but correct)
#pragma unroll 2
        for (int j = 0; j < HID; ++j) {
            float w[4];
#pragma unroll
            for (int r = 0; r < 4; ++r) w[r] = W1[(size_t)(it*4 + r)*HID + j];
            const float4 ma = *(const float4*)(&M0[j*SCP + ct*8]);
            const float4 mb = *(const float4*)(&M0[j*SCP + ct*8 + 4]);
            const float m[8] = {ma.x, ma.y, ma.z, ma.w, mb.x, mb.y, mb.z, mb.w};
#pragma unroll
            for (int r = 0; r < 4; ++r)
#pragma unroll
                for (int c = 0; c < 8; ++c)
                    acc[r][c] = fmaf(w[r], m[c], acc[r][c]);
        }
    }

    // ---- Epilogue 1: layer-2 nonlinearity + reverse seed ------------------
    {
#pragma unroll
        for (int r = 0; r < 4; ++r) {
            const int i = it*4 + r;
            const float b1i = b1[i];
            const float w2i = W2[i];
#pragma unroll
            for (int cs = 0; cs < 2; ++cs) {
                const float z1 = acc[r][cs*4+0] + b1i;
                const float h1 = tanhf(z1);
                const float s1 = 1.0f - h1*h1;
                const float u1 = w2i * s1;                 // dL/dz1
                const float m2 = -2.0f * w2i * h1 * s1;    // du1 = m2 * dz1
                float4 uv;
                uv.x = u1;
                uv.y = m2 * acc[r][cs*4+1];
                uv.z = m2 * acc[r][cs*4+2];
                uv.w = m2 * acc[r][cs*4+3];
                *(float4*)(&U[i*SCP + ct*8 + cs*4]) = uv;
            }
        }
    }
    __syncthreads();

    // ---- Phase 2: P[j][sc] = sum_i W1[i][j] * U[i][sc] (rows coalesced) ---
    float acc2[4][8];
#pragma unroll
    for (int r = 0; r < 4; ++r)
#pragma unroll
        for (int c = 0; c < 8; ++c) acc2[r][c] = 0.0f;

#pragma unroll 4
    for (int i = 0; i < HID; ++i) {
        const float4 w4 = *(const float4*)(W1 + (size_t)i*HID + it*4);
        const float4 ua = *(const float4*)(&U[i*SCP + ct*8]);       // broadcast
        const float4 ub = *(const float4*)(&U[i*SCP + ct*8 + 4]);   // broadcast
        const float w[4] = {w4.x, w4.y, w4.z, w4.w};
        const float m[8] = {ua.x, ua.y, ua.z, ua.w, ub.x, ub.y, ub.z, ub.w};
#pragma unroll
        for (int r = 0; r < 4; ++r)
#pragma unroll
            for (int c = 0; c < 8; ++c)
                acc2[r][c] = fmaf(w[r], m[c], acc2[r][c]);
    }
    __syncthreads();    // all U (u1/du1) reads complete before overwrite

    // ---- Epilogue 2: back through layer-0 nonlinearity --> u0, du0 --------
    {
#pragma unroll
        for (int r = 0; r < 4; ++r) {
            const int j = it*4 + r;
#pragma unroll
            for (int cs = 0; cs < 2; ++cs) {
                const int scb = ct*8 + cs*4;
                const float4 mm = *(const float4*)(&M0[j*SCP + scb]); // h0, dh0_k
                const float h0v = mm.x;
                const float sg  = 1.0f - h0v*h0v;
                const float p   = acc2[r][cs*4+0];
                const float t2  = -2.0f * p * h0v;
                float4 uv;
                uv.x = p * sg;                                   // u0
                uv.y = fmaf(acc2[r][cs*4+1], sg, t2 * mm.y);     // du0_k
                uv.z = fmaf(acc2[r][cs*4+2], sg, t2 * mm.z);
                uv.w = fmaf(acc2[r][cs*4+3], sg, t2 * mm.w);
                *(float4*)(&U[j*SCP + scb]) = uv;
            }
        }
    }
    __syncthreads();

    // ---- Phase 3: project through W0^T, reduce, assemble, solve -----------
    const int s = tid >> 5;     // sample within tile (0..7)
    const int t = tid & 31;     // 32 threads per sample
    float part[25];             // [0..3]=grad d<4 ; [4+k*7+d]=hvp_k[d]
#pragma unroll
    for (int q = 0; q < 25; ++q) part[q] = 0.0f;

#pragma unroll
    for (int m = 0; m < 8; ++m) {
        const int j = t + 32*m;
        const float4 uv = *(const float4*)(&U[j*SCP + s*4]);  // banks (4j+4s)%32: spread
        float w0d[7];
#pragma unroll
        for (int d = 0; d < 7; ++d) w0d[d] = W0[j*7 + d];
#pragma unroll
        for (int d = 0; d < 4; ++d) part[d] = fmaf(uv.x, w0d[d], part[d]);
#pragma unroll
        for (int d = 0; d < 7; ++d) {
            part[4  + d] = fmaf(uv.y, w0d[d], part[4  + d]);
            part[11 + d] = fmaf(uv.z, w0d[d], part[11 + d]);
            part[18 + d] = fmaf(uv.w, w0d[d], part[18 + d]);
        }
    }
    // reduce across the 32 threads of this sample (stays within 32-lane half)
#pragma unroll
    for (int off = 16; off >= 1; off >>= 1)
#pragma unroll
        for (int q = 0; q < 25; ++q)
            part[q] += __shfl_xor(part[q], off, 64);

    if (t == 0) {
        const float* xs = x + (size_t)(samp0 + s)*7;
        const double x1 = xs[2], x2 = xs[3];
        const double dq0 = xs[4], dq1 = xs[5], dth = xs[6];

        double A[3][4];
#pragma unroll
        for (int i = 0; i < 3; ++i) {
            const double J0 = part[4 + i*7 + 0];
            const double J1 = part[4 + i*7 + 1];
            const double J2 = -x2*(double)part[4 + i*7 + 2] + x1*(double)part[4 + i*7 + 3];
            const double dL = (i == 0) ? (double)part[0]
                            : (i == 1) ? (double)part[1]
                            : (-x2*(double)part[2] + x1*(double)part[3]);
            A[i][0] = (double)part[4 + i*7 + 4] + (i == 0 ? EPS_REG : 0.0);
            A[i][1] = (double)part[4 + i*7 + 5] + (i == 1 ? EPS_REG : 0.0);
            A[i][2] = (double)part[4 + i*7 + 6] + (i == 2 ? EPS_REG : 0.0);
            A[i][3] = dL - (J0*dq0 + J1*dq1 + J2*dth);
        }
        // 3x3 Gaussian elimination with partial pivoting (fp64)
        for (int c = 0; c < 2; ++c) {
            int piv = c;
            double mx = fabs(A[c][c]);
            for (int rr = c + 1; rr < 3; ++rr) {
                const double v = fabs(A[rr][c]);
                if (v > mx) { mx = v; piv = rr; }
            }
            if (piv != c) {
                for (int cc = 0; cc < 4; ++cc) {
                    const double tmp = A[c][cc]; A[c][cc] = A[piv][cc]; A[piv][cc] = tmp;
                }
            }
            const double inv = 1.0 / A[c][c];
            for (int rr = c + 1; rr < 3; ++rr) {
                const double f = A[rr][c] * inv;
                for (int cc = c + 1; cc < 4; ++cc) A[rr][cc] -= f * A[c][cc];
            }
        }
        const double sol2 = A[2][3] / A[2][2];
        const double sol1 = (A[1][3] - A[1][2]*sol2) / A[1][1];
        const double sol0 = (A[0][3] - A[0][1]*sol1 - A[0][2]*sol2) / A[0][0];

        float* o = out + (size_t)(samp0 + s)*7;
        o[0] = (float)dq0;
        o[1] = (float)dq1;
        o[2] = (float)(-x2*dth);
        o[3] = (float)( x1*dth);
        o[4] = (float)sol0;
        o[5] = (float)sol1;
        o[6] = (float)sol2;
    }
}

extern "C" void kernel_launch(void* const* d_in, const int* in_sizes, int n_in,
                              void* d_out, int out_size, void* d_ws, size_t ws_size,
                              hipStream_t stream) {
    const float* x  = (const float*)d_in[0];
    const float* W0 = (const float*)d_in[1];
    const float* b0 = (const float*)d_in[2];
    const float* W1 = (const float*)d_in[3];
    const float* b1 = (const float*)d_in[4];
    const float* W2 = (const float*)d_in[5];
    // d_in[6] = b2 : unused (gradient of constant)
    float* out = (float*)d_out;

    const int B = in_sizes[0] / 7;
    const int useT = (ws_size >= (size_t)HID * HID * sizeof(float)) ? 1 : 0;
    float* W1T = (float*)d_ws;

    if (useT) transpose_w1<<<64, 256, 0, stream>>>(W1, W1T);
    lnn_fused<<<B / TS, THREADS, 0, stream>>>(x, W0, b0, W1, b1, W2, W1T, useT, out);
}